// Round 13
// baseline (1934.096 us; speedup 1.0000x reference)
//
#include <hip/hip_runtime.h>
#include <math.h>

typedef unsigned short u16;
typedef float f4v __attribute__((ext_vector_type(4)));
typedef _Float16 hfv8 __attribute__((ext_vector_type(8)));

// gfx950 MFMA: D = A(16x32 f16) * B(32x16 f16) + C(f32x4)
#define MFMAH(a,b,c) __builtin_amdgcn_mfma_f32_16x16x32_f16((a),(b),(c),0,0,0)

// ---------------- numeric helpers ----------------
__device__ __forceinline__ float bf2f(u16 x){
    unsigned int u = ((unsigned int)x) << 16;
    float f; __builtin_memcpy(&f, &u, 4); return f;
}
__device__ __forceinline__ u16 f2bf(float f){
    unsigned int u; __builtin_memcpy(&u, &f, 4);
    u += 0x7fffu + ((u >> 16) & 1u);
    return (u16)(u >> 16);
}
__device__ __forceinline__ u16 f2h(float f){
    _Float16 h = (_Float16)f;
    u16 b; __builtin_memcpy(&b, &h, 2); return b;
}
__device__ __forceinline__ float h2f(u16 b){
    _Float16 h; __builtin_memcpy(&h, &b, 2); return (float)h;
}
// mode: 0 = bf16 wire, 1 = f32 wire
__device__ __forceinline__ float ldmix(const void* p, long i, int mode){
    if (mode) return ((const float*)p)[i];
    return bf2f(((const u16*)p)[i]);
}
// single-instruction v_rcp_f32 (~1 ulp) instead of the precise-div sequence
__device__ __forceinline__ float frcp(float x){ return __builtin_amdgcn_rcpf(x); }
__device__ __forceinline__ float sigf(float x){ return frcp(1.0f+__expf(-x)); }
__device__ __forceinline__ float tanh_fast(float x){
    float e = __expf(2.0f*x);
    return 1.0f - 2.0f*frcp(1.0f+e);
}

// ---------------- sizes ----------------
#define BATCH 256
#define TLEN 168
#define HOR 24

// ---------------- workspace layout (bytes) ----------------
#define OFF_FLAG 0ull
#define OFF_SENT 16ull
#define OFF_CNT  128ull
#define OFF_WF   256ull          // f32 weights, 2180353 elems
#define OFF_UP   8721920ull      // packed enc_U  3*196608 u16 (f16)
#define OFF_WP   9901568ull      // packed enc_W  3*24576 u16 (f16)
#define OFF_DWP  10049024ull     // packed dec_W rows 0..767, 589824 u16 (f16)
#define OFF_DUP  11228672ull     // packed dec_U 196608 u16 (f16)
#define OFF_H0   11621888ull     // 65536 f32
#define OFF_H1   11884032ull     // 65536 f32
#define OFF_C    12146176ull     // 196608 f32
#define OFF_W1P  12932608ull     // packed att_W1 hi/lo f16: 3*131072 u16 = 786432 B
#define OFF_SP   13719040ull     // 65536 f32
#define OFF_E    13981184ull     // 3145728 B (bf16 E) -- written late by k_ext
// overlays inside the E region (all dead before k_ext runs):
#define OFF_PACK0 OFF_E                      // 524288 B
#define OFF_PACK1 (OFF_E + 524288ull)        // 524288 B
#define OFF_W2P   (OFF_E + 1048576ull)       // 393216 B
#define OFF_ENCOUT 17126912ull   // 33030144 u16 (f16)
#define OFF_PROJ 83187200ull     // 33030144 u16 (f16)
#define NEED_BYTES 149247488ull

// f32-element offsets inside the converted-weights region
#define W_ENCW 0
#define W_ENCU 73728
#define W_ENCB 663552
#define W_AW1  665856
#define W_AW2  862464
#define W_AV   1059072
#define W_DECW 1059840
#define W_DECU 1650432
#define W_DECB 1847040
#define W_EXTW 1847808
#define W_EXTB 1851904
#define W_O1W  1852160
#define W_O1B  2179840
#define W_O2W  2180096
#define W_O2B  2180352

__device__ const int c_wsz[15]  = {73728,589824,2304,196608,196608,768,590592,196608,768,4096,256,327680,256,256,1};
__device__ const int c_woff[15] = {W_ENCW,W_ENCU,W_ENCB,W_AW1,W_AW2,W_AV,W_DECW,W_DECU,W_DECB,W_EXTW,W_EXTB,W_O1W,W_O1B,W_O2W,W_O2B};

struct P15 { const void* p[15]; };

#define SENT_MAGIC 0x5AFE0000u
__device__ __forceinline__ void put_sent(char* ws, int idx){
    ((unsigned int*)(ws+OFF_SENT))[idx] = SENT_MAGIC | (unsigned int)idx;
}

// =========================================================================
// probe: decide wire dtype
// =========================================================================
__global__ __launch_bounds__(256) void k_probe(const u16* w16, char* ws)
{
    __shared__ float red[256];
    int tid = threadIdx.x;
    float mb = 0.0f;
    for (int i = tid; i < 2048; i += 256){
        float a = fabsf(bf2f(w16[i]));
        if (a > mb) mb = a;
    }
    red[tid] = mb;
    __syncthreads();
    if (tid == 0){
        for (int i = 1; i < 256; ++i) if (red[i] > mb) mb = red[i];
        *(int*)(ws+OFF_FLAG) = (mb > 1000.0f) ? 1 : 0;
        put_sent(ws, 0);
    }
}

// =========================================================================
// convert the 15 weight tensors to f32 in ws
// =========================================================================
__global__ __launch_bounds__(256) void k_convert(P15 in, char* ws)
{
    int mode = *(const int*)(ws+OFF_FLAG);
    float* F = (float*)(ws+OFF_WF);
    int y = blockIdx.y;
    int sz = c_wsz[y], off = c_woff[y];
    for (long i = (long)blockIdx.x*256 + threadIdx.x; i < sz; i += 256L*256L)
        F[off + i] = ldmix(in.p[y], i, mode);
    if (blockIdx.x==0 && blockIdx.y==0 && threadIdx.x==0) put_sent(ws, 1);
}

// =========================================================================
// pack: F(f32 row-major [K][N]) -> f16 MFMA B-frags (K=32 tiles)
// m=8..10: att_W1[n] hi+lo residual. m=11..13: att_W2[n] f16 k-pair layout.
// =========================================================================
__global__ __launch_bounds__(64) void k_pack(char* ws)
{
    const float* F = (const float*)(ws+OFF_WF);
    int m = blockIdx.y;
    if (m >= 11){
        const float* s = F + W_AW2 + (m-11)*65536;
        u16* d = (u16*)(ws+OFF_W2P) + (m-11)*65536;
        int i = blockIdx.x*64 + threadIdx.x;
        if (i < 65536){
            int k = i>>8, u = i&255;
            d[(k>>1)*512 + u*2 + (k&1)] = f2h(s[i]);
        }
        return;
    }
    const float* src; u16* dst; int K, N; int duo = 0;
    switch (m) {
      case 0: case 1: case 2:
        src = F + W_ENCU + m*196608; dst = (u16*)(ws+OFF_UP) + m*196608; K=256; N=768; break;
      case 3: case 4: case 5:
        src = F + W_ENCW + (m-3)*24576; dst = (u16*)(ws+OFF_WP) + (m-3)*24576; K=32; N=768; break;
      case 6:
        src = F + W_DECW; dst = (u16*)(ws+OFF_DWP); K=768; N=768; break;
      case 7:
        src = F + W_DECU; dst = (u16*)(ws+OFF_DUP); K=256; N=768; break;
      default:   // 8,9,10 -> att_W1[n], hi/lo f16
        src = F + W_AW1 + (m-8)*65536; dst = (u16*)(ws+OFF_W1P) + (m-8)*131072; K=256; N=256; duo=1; break;
    }
    int KT = K>>5, NT = N>>4;
    int tau = blockIdx.x;
    if (tau < KT*NT){
        int ct = tau / KT, kt = tau % KT;
        int l = threadIdx.x, q = l>>4, c = l&15;
        #pragma unroll
        for (int j = 0; j < 8; ++j){
            float v = src[(size_t)(kt*32 + q*8 + j)*N + ct*16 + c];
            u16 hi = f2h(v);
            size_t di = ((size_t)(ct*KT+kt)*64 + l)*8 + j;
            dst[di] = hi;
            if (duo) dst[65536 + di] = f2h(v - h2f(hi));
        }
    }
    if (blockIdx.x==0 && blockIdx.y==0 && threadIdx.x==0) put_sent(ws, 6);
}

// =========================================================================
// init: zero h0, C, pack0, counters
// =========================================================================
__global__ __launch_bounds__(256) void k_init(char* ws)
{
    long idx = (long)blockIdx.x*256 + threadIdx.x;
    if (idx < 65536) ((float*)(ws+OFF_H0))[idx] = 0.0f;
    else if (idx < 262144) ((float*)(ws+OFF_C))[idx-65536] = 0.0f;
    else if (idx < 393216) ((int*)(ws+OFF_PACK0))[idx-262144] = 0;
    if (idx < 32) ((unsigned*)(ws+OFF_CNT))[idx] = 0u;
}

// =========================================================================
// encoder GRU v2 (MFMA, f16 recurrence): grid (16,3), 256 thr (4 waves,
// 1 wave/SIMD -> 512-reg budget). ALL U B-fragments (z,r,n = 96 frags =
// 384 regs/wave) pinned in the unified VGPR/AGPR file; nU LDS eliminated
// (LDS 149.5KB -> 18KB; per-step LDS reads 200 -> 36 b128). Only enc_W
// (12 frags/wave/step) still streams from L2. Math/order identical to the
// round-4 kernel -> absmax bit-identical.
// =========================================================================
__global__ __launch_bounds__(256, 1) void k_enc(const void* __restrict__ enc_in,
                                                char* __restrict__ ws,
                                                u16* __restrict__ enc_out)
{
    const float* __restrict__ F = (const float*)(ws+OFF_WF);
    int mode = *(const int*)(ws+OFF_FLAG);
    const int n  = blockIdx.y;
    const int b0 = blockIdx.x*16;
    const int tid = threadIdx.x;
    const int w = tid>>6, l = tid&63, quad = l>>4, c15 = l&15;

    __shared__ __align__(16) u16 hA[2][8][64][8];    // 16 KB
    __shared__ __align__(16) u16 sx[2][64][8];       //  2 KB

    const u16* __restrict__ upn = (const u16*)(ws+OFF_UP) + n*196608;   // KT=8
    const u16* __restrict__ wpn = (const u16*)(ws+OFF_WP) + n*24576;    // KT=1

    {
        int* z0 = (int*)&hA[0][0][0][0];
        for (int i = tid; i < 2048; i += 256) z0[i]=0;
    }
    float h[16];
    #pragma unroll
    for (int i=0;i<16;++i) h[i]=0.0f;

    float bzr[4], brr[4], bnr[4];
    #pragma unroll
    for (int si=0;si<4;++si){
        int u = (w*4+si)*16 + c15;
        bzr[si] = F[W_ENCB + n*768 + u];
        brr[si] = F[W_ENCB + n*768 + 256 + u];
        bnr[si] = F[W_ENCB + n*768 + 512 + u];
    }

    // pin ALL loop-invariant U-fragments (z,r,n gates: 96 frags = 384 regs).
    // the empty asm is the defining op -> no remat, no re-load (r4-proven).
    hfv8 Bz[4][8], Br[4][8], Bn[4][8];
    #pragma unroll
    for (int si=0;si<4;++si){
        int ct = w*4+si;
        #pragma unroll
        for (int kt=0;kt<8;++kt){
            Bz[si][kt] = *(const hfv8*)(upn + ((size_t)(ct*8+kt)*64 + l)*8);
            Br[si][kt] = *(const hfv8*)(upn + ((size_t)((16+ct)*8+kt)*64 + l)*8);
            Bn[si][kt] = *(const hfv8*)(upn + ((size_t)((32+ct)*8+kt)*64 + l)*8);
        }
    }
    #pragma unroll
    for (int si=0;si<4;++si)
        #pragma unroll
        for (int kt=0;kt<8;++kt)
            asm volatile("" : "+v"(Bz[si][kt]), "+v"(Br[si][kt]), "+v"(Bn[si][kt]));

    // x staging map: 16 rows x 32 k = 512 slots, 2 per thread
    #pragma unroll
    for (int rep=0; rep<2; ++rep){
        int idx = tid + rep*256;
        int mm = idx>>5, kk2 = idx&31;
        sx[0][(kk2>>3)*16 + mm][kk2&7] =
            f2h(ldmix(enc_in, (((long)(n*BATCH + b0 + mm))*TLEN + 0)*32 + kk2, mode));
    }
    __syncthreads();

    for (int t = 0; t < TLEN; ++t){
        int p = t & 1;
        int tt = (t+1 < TLEN) ? (t+1) : t;
        // prefetch x(t+1) into registers; consumed only after the MFMA phase
        float xr0, xr1;
        {
            int idx0 = tid, idx1 = tid + 256;
            xr0 = ldmix(enc_in, (((long)(n*BATCH + b0 + (idx0>>5)))*TLEN + tt)*32 + (idx0&31), mode);
            xr1 = ldmix(enc_in, (((long)(n*BATCH + b0 + (idx1>>5)))*TLEN + tt)*32 + (idx1&31), mode);
        }

        hfv8 ah[8];
        #pragma unroll
        for (int kt=0; kt<8; ++kt)
            ah[kt] = *(const hfv8*)&hA[p][kt][l][0];
        hfv8 ax = *(const hfv8*)&sx[p][l][0];

        #pragma unroll
        for (int si=0; si<4; ++si){
            int ct = w*4 + si;
            f4v az  = {0.f,0.f,0.f,0.f};
            f4v ar  = {0.f,0.f,0.f,0.f};
            f4v anx = {0.f,0.f,0.f,0.f};
            f4v anh = {0.f,0.f,0.f,0.f};
            az  = MFMAH(ax, *(const hfv8*)(wpn + ((size_t)ct*64 + l)*8), az);
            ar  = MFMAH(ax, *(const hfv8*)(wpn + ((size_t)(16+ct)*64 + l)*8), ar);
            anx = MFMAH(ax, *(const hfv8*)(wpn + ((size_t)(32+ct)*64 + l)*8), anx);
            #pragma unroll
            for (int kt=0; kt<8; ++kt) az = MFMAH(ah[kt], Bz[si][kt], az);
            #pragma unroll
            for (int kt=0; kt<8; ++kt) ar = MFMAH(ah[kt], Br[si][kt], ar);
            #pragma unroll
            for (int kt=0; kt<8; ++kt) anh = MFMAH(ah[kt], Bn[si][kt], anh);
            int u = ct*16 + c15;
            #pragma unroll
            for (int j=0;j<4;++j){
                int m = quad*4 + j;
                float z = sigf(az[j] + bzr[si]);
                float r = sigf(ar[j] + brr[si]);
                float ng = tanh_fast(anx[j] + bnr[si] + r*anh[j]);
                float hn = (1.0f - z)*h[si*4+j] + z*ng;
                h[si*4+j] = hn;
                int kt = u>>5, q2 = (u>>3)&3, j2 = u&7;
                hA[1-p][kt][q2*16+m][j2] = f2h(hn);
            }
        }
        // commit prefetched x(t+1)
        {
            int idx0 = tid, idx1 = tid + 256;
            sx[1-p][((idx0&31)>>3)*16 + (idx0>>5)][idx0&7] = f2h(xr0);
            sx[1-p][((idx1&31)>>3)*16 + (idx1>>5)][idx1&7] = f2h(xr1);
        }
        __syncthreads();
        // coalesced enc_out (f16) store of row t: 2 uint4 per thread
        #pragma unroll
        for (int rep=0; rep<2; ++rep){
            int idx = tid + rep*256;
            int c = idx & 31, m2 = idx >> 5;
            *reinterpret_cast<uint4*>(enc_out + (((long)(n*BATCH + b0 + m2))*TLEN + t)*256 + c*8) =
                *(const uint4*)&hA[1-p][c>>2][(c&3)*16 + m2][0];
        }
    }
    if (blockIdx.x==0 && blockIdx.y==0 && tid==0) put_sent(ws, 2);
}

// =========================================================================
// proj = enc_out @ att_W1[n] via f16 MFMA (W1 hi+lo -> ~f32 weight accuracy)
// grid (672 rowtiles64, 3), 256 thr (4 waves x 16 rows each)
// =========================================================================
__global__ __launch_bounds__(256) void k_projm(char* __restrict__ ws)
{
    const u16* __restrict__ enc16 = (const u16*)(ws+OFF_ENCOUT);
    const u16* __restrict__ w1p = (const u16*)(ws+OFF_W1P);
    u16* __restrict__ proj = (u16*)(ws+OFF_PROJ);
    const int n = blockIdx.y;
    const long r0 = (long)blockIdx.x*64;
    const int tid = threadIdx.x;
    const int w = tid>>6, l = tid&63, quad = l>>4, c15 = l&15;

    __shared__ __align__(16) u16 ob[64][264];

    const u16* erow = enc16 + ((long)n*43008 + r0 + w*16 + c15)*256;
    hfv8 a[8];
    #pragma unroll
    for (int kt=0; kt<8; ++kt)
        a[kt] = *(const hfv8*)(erow + kt*32 + quad*8);

    const u16* wb = w1p + (long)n*131072;
    #pragma unroll
    for (int ct=0; ct<16; ++ct){
        f4v acc = {0.f,0.f,0.f,0.f};
        #pragma unroll
        for (int kt=0; kt<8; ++kt)
            acc = MFMAH(a[kt], *(const hfv8*)(wb + ((size_t)(ct*8+kt)*64 + l)*8), acc);
        #pragma unroll
        for (int kt=0; kt<8; ++kt)
            acc = MFMAH(a[kt], *(const hfv8*)(wb + 65536 + ((size_t)(ct*8+kt)*64 + l)*8), acc);
        #pragma unroll
        for (int j=0;j<4;++j)
            ob[w*16 + quad*4 + j][ct*16 + c15] = f2h(acc[j]);
    }
    __syncthreads();
    for (int i = tid; i < 2048; i += 256){
        int r = i>>5, c = i&31;
        *reinterpret_cast<uint4*>(proj + ((long)n*43008 + r0 + r)*256 + c*8) =
            *(const uint4*)&ob[r][c*8];
    }
    if (blockIdx.x==0 && blockIdx.y==0 && tid==0) put_sent(ws, 3);
}

// =========================================================================
// decoder GRU step: grid (16 rowtiles16, 16 u-slices), 192 thr (wave=gate).
// A ([c,h] 16x1024) read PRE-PACKED f16 from ping-pong pack buffers.
// (round-4 proven version, unchanged)
// =========================================================================
__global__ __launch_bounds__(192) void k_dec_gru(
    char* __restrict__ ws, const float* __restrict__ h_in, float* __restrict__ h_out,
    const u16* __restrict__ packC, u16* __restrict__ packN,
    const void* __restrict__ dec_in, int step)
{
    const float* __restrict__ F = (const float*)(ws+OFF_WF);
    int mode = *(const int*)(ws+OFF_FLAG);
    const u16* __restrict__ dwp = (const u16*)(ws+OFF_DWP);   // KT=24
    const u16* __restrict__ dup = (const u16*)(ws+OFF_DUP);   // KT=8
    const int bx = blockIdx.x;
    const int b0 = bx*16;
    const int us = blockIdx.y;
    const int u0 = us*16;
    const int tid = threadIdx.x;
    const int gate = tid>>6, l = tid&63, quad = l>>4, c15 = l&15;
    const int ct = gate*16 + us;

    __shared__ float gz[16][16], gr[16][16], gx[16][16], gh[16][16];

    const u16* pA = packC + (size_t)bx*16384;   // [32][64][8] u16

    f4v accA  = {0.f,0.f,0.f,0.f};
    f4v accA2 = {0.f,0.f,0.f,0.f};
    f4v accB  = {0.f,0.f,0.f,0.f};
    f4v accB2 = {0.f,0.f,0.f,0.f};

    #pragma unroll
    for (int kg = 0; kg < 32; ++kg){
        hfv8 av = *(const hfv8*)(pA + ((size_t)kg*64 + l)*8);
        const u16* bp = (kg < 24) ? dwp + ((size_t)(ct*24 + kg)*64 + l)*8
                                  : dup + ((size_t)(ct*8  + (kg-24))*64 + l)*8;
        hfv8 bv = *(const hfv8*)bp;
        if (gate == 2 && kg >= 24){
            if (kg & 1) accB2 = MFMAH(av, bv, accB2);
            else        accB  = MFMAH(av, bv, accB);
        } else {
            if (kg & 1) accA2 = MFMAH(av, bv, accA2);
            else        accA  = MFMAH(av, bv, accA);
        }
    }
    accA = accA + accA2;
    accB = accB + accB2;

    #pragma unroll
    for (int j=0;j<4;++j){
        int m = quad*4 + j;
        if (gate == 0) gz[m][c15] = accA[j];
        else if (gate == 1) gr[m][c15] = accA[j];
        else { gx[m][c15] = accA[j]; gh[m][c15] = accB[j]; }
    }
    __syncthreads();
    for (int e = tid; e < 256; e += 192){
        int m = e>>4, j = e&15;
        int u = u0 + j;
        int b = b0 + m;
        float db = ldmix(dec_in, (long)b*HOR + step, mode);
        float sz = gz[m][j] + db*F[W_DECW + 768*768 + u]       + F[W_DECB + u];
        float sr = gr[m][j] + db*F[W_DECW + 768*768 + 256 + u] + F[W_DECB + 256 + u];
        float sn = gx[m][j] + db*F[W_DECW + 768*768 + 512 + u] + F[W_DECB + 512 + u];
        float z = sigf(sz);
        float r = sigf(sr);
        float ng = tanh_fast(sn + r*gh[m][j]);
        float hn = (1.0f - z)*h_in[(long)b*256 + u] + z*ng;
        h_out[(long)b*256 + u] = hn;
        // packed h (kg 24..31) for next step's A
        int kk = u & 31;
        int kg = 24 + (u >> 5);
        packN[(((size_t)bx*32 + kg)*64 + (kk>>3)*16 + m)*8 + (kk&7)] = f2h(hn);
    }
}

// =========================================================================
// attention v5 (round-10/12 proven BEST): grid (256 b, 3 n), 512 thr.
// - q-phase k-split across two half-blocks
// - phase 1: 8 waves x 21 t, 4 INDEPENDENT scalar loads per t
// - ctx: t-split across two half-blocks, 8 accumulator chains each
// =========================================================================
__global__ __launch_bounds__(512) void k_attn(char* __restrict__ ws,
                                              const float* __restrict__ hvec,
                                              u16* __restrict__ packN)
{
    const float* __restrict__ F = (const float*)(ws+OFF_WF);
    const u16* __restrict__ proj = (const u16*)(ws+OFF_PROJ);
    const u16* __restrict__ enc16 = (const u16*)(ws+OFF_ENCOUT);
    float* __restrict__ C = (float*)(ws+OFF_C);
    const int b = blockIdx.x, n = blockIdx.y;
    const int tid = threadIdx.x;
    const int w = tid>>6, l = tid&63;

    __shared__ float ps[TLEN][65];
    __shared__ float sc[TLEN];
    __shared__ float red[16];
    __shared__ float hrow[256];
    __shared__ float sq[256];
    __shared__ float sqp[2][256];
    __shared__ float ctxp[2][256];

    if (tid < 256) hrow[tid] = hvec[(long)b*256 + tid];
    __syncthreads();

    // q-phase: q[u] = sum_k h[b][k]*W2[n][k][u]; k-range split across halves
    {
        const u16* W2p = (const u16*)(ws+OFF_W2P) + n*65536;
        int uu = tid & 255, half = tid >> 8;
        float q0=0.f,q1=0.f,q2=0.f,q3=0.f;
        #pragma unroll 4
        for (int k2 = half*64; k2 < half*64+64; k2 += 2){
            unsigned va = *(const unsigned*)(W2p + (size_t)k2*512 + uu*2);
            unsigned vb = *(const unsigned*)(W2p + (size_t)(k2+1)*512 + uu*2);
            q0 += hrow[2*k2  ]*h2f((u16)(va & 0xffffu));
            q1 += hrow[2*k2+1]*h2f((u16)(va >> 16));
            q2 += hrow[2*k2+2]*h2f((u16)(vb & 0xffffu));
            q3 += hrow[2*k2+3]*h2f((u16)(vb >> 16));
        }
        sqp[half][uu] = (q0+q1)+(q2+q3);
    }
    __syncthreads();
    if (tid < 256) sq[tid] = sqp[0][tid] + sqp[1][tid];
    __syncthreads();

    float qv[4], vv[4];
    #pragma unroll
    for (int c4 = 0; c4 < 4; ++c4){
        qv[c4] = sq[c4*64 + l];
        vv[c4] = F[W_AV + n*256 + c4*64 + l];
    }
    long base = ((long)n*43008 + (long)b*TLEN)*256;
    const u16* pb = proj + base;

    // phase 1: per-(t,lane) partials, 8 waves x 21 t each
    for (int i = 0; i < 21; ++i){
        int t = w*21 + i;
        float s = 0.0f;
        #pragma unroll
        for (int c4 = 0; c4 < 4; ++c4){
            float pv = h2f(pb[(long)t*256 + c4*64 + l]);
            s += vv[c4]*tanh_fast(pv + qv[c4]);
        }
        ps[t][l] = s;
    }
    __syncthreads();

    // phase 2: lane-sum with 8 independent chains (t = tid < 168)
    float sval = 0.0f;
    if (tid < TLEN){
        float s0=0.f,s1=0.f,s2=0.f,s3=0.f,s4=0.f,s5=0.f,s6=0.f,s7=0.f;
        #pragma unroll
        for (int j = 0; j < 64; j += 8){
            s0 += ps[tid][j];   s1 += ps[tid][j+1];
            s2 += ps[tid][j+2]; s3 += ps[tid][j+3];
            s4 += ps[tid][j+4]; s5 += ps[tid][j+5];
            s6 += ps[tid][j+6]; s7 += ps[tid][j+7];
        }
        sval = ((s0+s1)+(s2+s3)) + ((s4+s5)+(s6+s7));
    }

    // parallel max (butterfly + 8-way LDS combine)
    float m = (tid < TLEN) ? sval : -1e30f;
    #pragma unroll
    for (int off = 32; off > 0; off >>= 1) m = fmaxf(m, __shfl_xor(m, off, 64));
    if (l == 0) red[w] = m;
    __syncthreads();
    float mx = fmaxf(fmaxf(fmaxf(red[0],red[1]), fmaxf(red[2],red[3])),
                     fmaxf(fmaxf(red[4],red[5]), fmaxf(red[6],red[7])));

    // exp + parallel sum
    float ex = 0.0f;
    if (tid < TLEN){ ex = __expf(sval - mx); sc[tid] = ex; }
    float su = ex;
    #pragma unroll
    for (int off = 32; off > 0; off >>= 1) su += __shfl_xor(su, off, 64);
    if (l == 0) red[8+w] = su;
    __syncthreads();
    float inv = frcp(((red[8]+red[9])+(red[10]+red[11])) +
                     ((red[12]+red[13])+(red[14]+red[15])));

    // ctx: t-range split across two half-blocks, 8 chains each (88=11*8, 80=10*8)
    {
        const u16* eb = enc16 + base;
        int uu = tid & 255, half = tid >> 8;
        int t0 = half ? 88 : 0;
        int t1 = half ? 168 : 88;
        float a0=0.f,a1=0.f,a2=0.f,a3=0.f,a4=0.f,a5=0.f,a6=0.f,a7=0.f;
        for (int t = t0; t < t1; t += 8){
            a0 += sc[t  ]*h2f(eb[(long)(t  )*256 + uu]);
            a1 += sc[t+1]*h2f(eb[(long)(t+1)*256 + uu]);
            a2 += sc[t+2]*h2f(eb[(long)(t+2)*256 + uu]);
            a3 += sc[t+3]*h2f(eb[(long)(t+3)*256 + uu]);
            a4 += sc[t+4]*h2f(eb[(long)(t+4)*256 + uu]);
            a5 += sc[t+5]*h2f(eb[(long)(t+5)*256 + uu]);
            a6 += sc[t+6]*h2f(eb[(long)(t+6)*256 + uu]);
            a7 += sc[t+7]*h2f(eb[(long)(t+7)*256 + uu]);
        }
        ctxp[half][uu] = (((a0+a1)+(a2+a3)) + ((a4+a5)+(a6+a7)));
    }
    __syncthreads();
    if (tid < 256){
        float cv = (ctxp[0][tid] + ctxp[1][tid])*inv;
        C[(long)b*768 + n*256 + tid] = cv;
        int kg = n*8 + (tid>>5), kk = tid&31;
        packN[(((size_t)(b>>4)*32 + kg)*64 + (kk>>3)*16 + (b&15))*8 + (kk&7)] = f2h(cv);
    }
    if (b==0 && n==0 && tid==0) put_sent(ws, 4);
}

// =========================================================================
// head1: sp = [h,c] @ out1_W[0:1024] : grid 32 rowtiles8, 256 thr
// =========================================================================
__global__ __launch_bounds__(256) void k_head1(char* ws, const float* h_last)
{
    const float* F = (const float*)(ws+OFF_WF);
    const float* C = (const float*)(ws+OFF_C);
    float* SP = (float*)(ws+OFF_SP);
    const int b0 = blockIdx.x*8;
    const int tid = threadIdx.x;

    __shared__ float A[8][1024];
    for (int i = tid; i < 8192; i += 256){
        int r = i >> 10, k = i & 1023;
        A[r][k] = (k < 256) ? h_last[(long)(b0+r)*256 + k]
                            : C[(long)(b0+r)*768 + (k-256)];
    }
    __syncthreads();

    const float* W = F + W_O1W;
    float acc[8];
    float bc = F[W_O1B + tid];
    #pragma unroll
    for (int r = 0; r < 8; ++r) acc[r] = bc;
    for (int k = 0; k < 1024; ++k){
        float w = W[k*256 + tid];
        #pragma unroll
        for (int r = 0; r < 8; ++r) acc[r] += A[r][k]*w;
    }
    for (int r = 0; r < 8; ++r)
        SP[(long)(b0+r)*256 + tid] = acc[r];
}

// =========================================================================
// ext: E = relu(ext_feat @ ext_W + ext_b) -> bf16 : grid 96, 256 thr
// =========================================================================
__global__ __launch_bounds__(256) void k_ext(const void* ext_feat, char* ws)
{
    const float* F = (const float*)(ws+OFF_WF);
    u16* E = (u16*)(ws+OFF_E);
    int mode = *(const int*)(ws+OFF_FLAG);
    const int r0 = blockIdx.x*64;
    const int tid = threadIdx.x;
    __shared__ float ef[64][16];
    for (int i = tid; i < 1024; i += 256)
        ef[i>>4][i&15] = ldmix(ext_feat, (long)(r0 + (i>>4))*16 + (i&15), mode);
    float wreg[16];
    #pragma unroll
    for (int k = 0; k < 16; ++k) wreg[k] = F[W_EXTW + k*256 + tid];
    float bb = F[W_EXTB + tid];
    __syncthreads();
    for (int r = 0; r < 64; ++r){
        float a = bb;
        #pragma unroll
        for (int k = 0; k < 16; ++k) a += ef[r][k]*wreg[k];
        E[(long)(r0+r)*256 + tid] = f2bf((a > 0.0f) ? a : 0.0f);
    }
}

// =========================================================================
// head2: x1 = relu(sp[b] + E@out1_W[1024:] + b1); out = x1@out2_W + b2
// =========================================================================
__global__ __launch_bounds__(256) void k_head2(char* ws, void* out)
{
    const float* F = (const float*)(ws+OFF_WF);
    const u16* E = (const u16*)(ws+OFF_E);
    const float* SP = (const float*)(ws+OFF_SP);
    int mode = *(const int*)(ws+OFF_FLAG);
    const int r0 = blockIdx.x*16;
    const int tid = threadIdx.x;
    const int w = tid>>6, l = tid&63;

    __shared__ float A[16][256];
    __shared__ float x1[16][257];
    for (int i = tid; i < 4096; i += 256)
        A[i>>8][i&255] = bf2f(E[(long)r0*256 + i]);
    __syncthreads();

    const float* W = F + W_O1W + 1024*256;
    float acc[16];
    float bc = F[W_O1B + tid];
    #pragma unroll
    for (int r = 0; r < 16; ++r) acc[r] = 0.0f;
    for (int k = 0; k < 256; ++k){
        float wv = W[k*256 + tid];
        #pragma unroll
        for (int r = 0; r < 16; ++r) acc[r] += A[r][k]*wv;
    }
    for (int r = 0; r < 16; ++r){
        int g = r0 + r;
        int b = g / HOR;
        float v = acc[r] + SP[(long)b*256 + tid] + bc;
        x1[r][tid] = (v > 0.0f) ? v : 0.0f;
    }
    __syncthreads();

    float w2v[4];
    #pragma unroll
    for (int c4 = 0; c4 < 4; ++c4) w2v[c4] = F[W_O2W + c4*64 + l];
    float b2 = F[W_O2B];
    #pragma unroll
    for (int rr = 0; rr < 4; ++rr){
        int m = w*4 + rr;
        float s = 0.0f;
        #pragma unroll
        for (int c4 = 0; c4 < 4; ++c4) s += x1[m][c4*64 + l]*w2v[c4];
        for (int off = 32; off > 0; off >>= 1) s += __shfl_xor(s, off, 64);
        if (l == 0){
            float val = s + b2;
            long g = r0 + m;
            if (mode == 0) ((u16*)out)[g] = f2bf(val);
            else           ((float*)out)[g] = val;
        }
    }
    if (blockIdx.x==0 && tid==0) put_sent(ws, 5);
}

// =========================================================================
// checker: writes 400+10*i to out[0] if sentinel i missing
// =========================================================================
__global__ __launch_bounds__(64) void MTANet_7593502179851_kernel(char* ws, void* out)
{
    if (threadIdx.x == 0){
        const unsigned int* sent = (const unsigned int*)(ws+OFF_SENT);
        int mode = *(const int*)(ws+OFF_FLAG);
        for (int i = 0; i < 7; ++i){
            if (sent[i] != (SENT_MAGIC | (unsigned int)i)){
                float code = 400.0f + 10.0f*(float)i;
                if (mode == 0) ((u16*)out)[0] = f2bf(code);
                else           ((float*)out)[0] = code;
                break;
            }
        }
    }
}

__global__ __launch_bounds__(64) void k_diag(void* out, float code)
{
    if (threadIdx.x == 0){
        ((u16*)out)[0] = f2bf(code);
        ((float*)out)[1] = code;
    }
}

// =========================================================================
extern "C" void kernel_launch(void* const* d_in, const int* in_sizes, int n_in,
                              void* d_out, int out_size, void* d_ws, size_t ws_size,
                              hipStream_t stream)
{
    char* ws = (char*)d_ws;

    static const int exp_sizes[18] = {
        4128768, 6144, 98304, 73728, 589824, 2304, 196608, 196608, 768,
        590592, 196608, 768, 4096, 256, 327680, 256, 256, 1 };
    int bad_i = -1;
    if (n_in != 18) bad_i = 99;
    else for (int i = 0; i < 18; ++i)
        if (in_sizes[i] != exp_sizes[i]){ bad_i = i; break; }
    if (bad_i >= 0){
        k_diag<<<dim3(1), dim3(64), 0, stream>>>(d_out, 900.0f + (float)bad_i);
        return;
    }
    if (ws_size < (size_t)NEED_BYTES){
        k_diag<<<dim3(1), dim3(64), 0, stream>>>(d_out, 600.0f);
        return;
    }

    P15 wp;
    for (int i = 0; i < 15; ++i) wp.p[i] = d_in[3+i];

    hipError_t le[12];
    for (int i = 0; i < 12; ++i) le[i] = hipSuccess;
    (void)hipGetLastError();
    #define CHK(slot) { hipError_t e_ = hipGetLastError(); if (e_ != hipSuccess && le[slot] == hipSuccess) le[slot] = e_; }

    k_probe<<<dim3(1), dim3(256), 0, stream>>>((const u16*)d_in[3], ws);       CHK(0)
    k_convert<<<dim3(256,15), dim3(256), 0, stream>>>(wp, ws);                 CHK(1)
    k_pack<<<dim3(1152,14), dim3(64), 0, stream>>>(ws);                        CHK(2)
    k_init<<<dim3(1536), dim3(256), 0, stream>>>(ws);                          CHK(3)
    k_enc<<<dim3(16,3), dim3(256), 0, stream>>>(d_in[0], ws, (u16*)(ws+OFF_ENCOUT)); CHK(4)
    k_projm<<<dim3(672,3), dim3(256), 0, stream>>>(ws);                        CHK(5)

    float* hbuf0 = (float*)(ws+OFF_H0);
    float* hbuf1 = (float*)(ws+OFF_H1);
    u16* pk0 = (u16*)(ws+OFF_PACK0);
    u16* pk1 = (u16*)(ws+OFF_PACK1);
    float* h_last = hbuf0;
    for (int s = 0; s < HOR; ++s){
        float* h_in  = (s & 1) ? hbuf1 : hbuf0;
        float* h_out = (s & 1) ? hbuf0 : hbuf1;
        u16* pc = (s & 1) ? pk1 : pk0;
        u16* pn = (s & 1) ? pk0 : pk1;
        k_dec_gru<<<dim3(16,16), dim3(192), 0, stream>>>(ws, h_in, h_out, pc, pn, d_in[1], s); CHK(6)
        k_attn<<<dim3(256,3), dim3(512), 0, stream>>>(ws, h_out, pn);           CHK(7)
        h_last = h_out;
    }
    k_head1<<<dim3(32), dim3(256), 0, stream>>>(ws, h_last);                   CHK(8)
    k_ext<<<dim3(96), dim3(256), 0, stream>>>(d_in[2], ws);                    CHK(9)
    k_head2<<<dim3(384), dim3(256), 0, stream>>>(ws, d_out);                   CHK(10)
    MTANet_7593502179851_kernel<<<dim3(1), dim3(64), 0, stream>>>(ws, d_out);
    #undef CHK

    for (int i = 0; i < 12; ++i){
        if (le[i] != hipSuccess){
            k_diag<<<dim3(1), dim3(64), 0, stream>>>(d_out, 800.0f + (float)i);
            break;
        }
    }
}

// Round 14
// 1513.562 us; speedup vs baseline: 1.2778x; 1.2778x over previous
//
#include <hip/hip_runtime.h>
#include <math.h>

typedef unsigned short u16;
typedef float f4v __attribute__((ext_vector_type(4)));
typedef _Float16 hfv8 __attribute__((ext_vector_type(8)));

// gfx950 MFMA: D = A(16x32 f16) * B(32x16 f16) + C(f32x4)
#define MFMAH(a,b,c) __builtin_amdgcn_mfma_f32_16x16x32_f16((a),(b),(c),0,0,0)

// ---------------- numeric helpers ----------------
__device__ __forceinline__ float bf2f(u16 x){
    unsigned int u = ((unsigned int)x) << 16;
    float f; __builtin_memcpy(&f, &u, 4); return f;
}
__device__ __forceinline__ u16 f2bf(float f){
    unsigned int u; __builtin_memcpy(&u, &f, 4);
    u += 0x7fffu + ((u >> 16) & 1u);
    return (u16)(u >> 16);
}
__device__ __forceinline__ u16 f2h(float f){
    _Float16 h = (_Float16)f;
    u16 b; __builtin_memcpy(&b, &h, 2); return b;
}
__device__ __forceinline__ float h2f(u16 b){
    _Float16 h; __builtin_memcpy(&h, &b, 2); return (float)h;
}
// mode: 0 = bf16 wire, 1 = f32 wire
__device__ __forceinline__ float ldmix(const void* p, long i, int mode){
    if (mode) return ((const float*)p)[i];
    return bf2f(((const u16*)p)[i]);
}
// single-instruction v_rcp_f32 (~1 ulp) instead of the precise-div sequence
__device__ __forceinline__ float frcp(float x){ return __builtin_amdgcn_rcpf(x); }
__device__ __forceinline__ float sigf(float x){ return frcp(1.0f+__expf(-x)); }
__device__ __forceinline__ float tanh_fast(float x){
    float e = __expf(2.0f*x);
    return 1.0f - 2.0f*frcp(1.0f+e);
}

// ---------------- sizes ----------------
#define BATCH 256
#define TLEN 168
#define HOR 24

// ---------------- workspace layout (bytes) ----------------
#define OFF_FLAG 0ull
#define OFF_SENT 16ull
#define OFF_CNT  128ull
#define OFF_WF   256ull          // f32 weights, 2180353 elems
#define OFF_UP   8721920ull      // packed enc_U  3*196608 u16 (f16)
#define OFF_WP   9901568ull      // packed enc_W  3*24576 u16 (f16)
#define OFF_DWP  10049024ull     // packed dec_W rows 0..767, 589824 u16 (f16)
#define OFF_DUP  11228672ull     // packed dec_U 196608 u16 (f16)
#define OFF_H0   11621888ull     // 65536 f32
#define OFF_H1   11884032ull     // 65536 f32
#define OFF_C    12146176ull     // 196608 f32
#define OFF_W1P  12932608ull     // packed att_W1 hi/lo f16: 3*131072 u16 = 786432 B
#define OFF_SP   13719040ull     // 65536 f32
#define OFF_E    13981184ull     // 3145728 B (bf16 E) -- written late by k_ext
// overlays inside the E region (all dead before k_ext runs):
#define OFF_PACK0 OFF_E                      // 524288 B
#define OFF_PACK1 (OFF_E + 524288ull)        // 524288 B
#define OFF_W2P   (OFF_E + 1048576ull)       // 393216 B
#define OFF_ENCOUT 17126912ull   // 33030144 u16 (f16)
#define OFF_PROJ 83187200ull     // 33030144 u16 (f16)
#define NEED_BYTES 149247488ull

// f32-element offsets inside the converted-weights region
#define W_ENCW 0
#define W_ENCU 73728
#define W_ENCB 663552
#define W_AW1  665856
#define W_AW2  862464
#define W_AV   1059072
#define W_DECW 1059840
#define W_DECU 1650432
#define W_DECB 1847040
#define W_EXTW 1847808
#define W_EXTB 1851904
#define W_O1W  1852160
#define W_O1B  2179840
#define W_O2W  2180096
#define W_O2B  2180352

__device__ const int c_wsz[15]  = {73728,589824,2304,196608,196608,768,590592,196608,768,4096,256,327680,256,256,1};
__device__ const int c_woff[15] = {W_ENCW,W_ENCU,W_ENCB,W_AW1,W_AW2,W_AV,W_DECW,W_DECU,W_DECB,W_EXTW,W_EXTB,W_O1W,W_O1B,W_O2W,W_O2B};

struct P15 { const void* p[15]; };

#define SENT_MAGIC 0x5AFE0000u
__device__ __forceinline__ void put_sent(char* ws, int idx){
    ((unsigned int*)(ws+OFF_SENT))[idx] = SENT_MAGIC | (unsigned int)idx;
}

// =========================================================================
// probe: decide wire dtype
// =========================================================================
__global__ __launch_bounds__(256) void k_probe(const u16* w16, char* ws)
{
    __shared__ float red[256];
    int tid = threadIdx.x;
    float mb = 0.0f;
    for (int i = tid; i < 2048; i += 256){
        float a = fabsf(bf2f(w16[i]));
        if (a > mb) mb = a;
    }
    red[tid] = mb;
    __syncthreads();
    if (tid == 0){
        for (int i = 1; i < 256; ++i) if (red[i] > mb) mb = red[i];
        *(int*)(ws+OFF_FLAG) = (mb > 1000.0f) ? 1 : 0;
        put_sent(ws, 0);
    }
}

// =========================================================================
// convert the 15 weight tensors to f32 in ws
// =========================================================================
__global__ __launch_bounds__(256) void k_convert(P15 in, char* ws)
{
    int mode = *(const int*)(ws+OFF_FLAG);
    float* F = (float*)(ws+OFF_WF);
    int y = blockIdx.y;
    int sz = c_wsz[y], off = c_woff[y];
    for (long i = (long)blockIdx.x*256 + threadIdx.x; i < sz; i += 256L*256L)
        F[off + i] = ldmix(in.p[y], i, mode);
    if (blockIdx.x==0 && blockIdx.y==0 && threadIdx.x==0) put_sent(ws, 1);
}

// =========================================================================
// pack: F(f32 row-major [K][N]) -> f16 MFMA B-frags (K=32 tiles)
// m=8..10: att_W1[n] hi+lo residual. m=11..13: att_W2[n] f16 k-pair layout.
// =========================================================================
__global__ __launch_bounds__(64) void k_pack(char* ws)
{
    const float* F = (const float*)(ws+OFF_WF);
    int m = blockIdx.y;
    if (m >= 11){
        const float* s = F + W_AW2 + (m-11)*65536;
        u16* d = (u16*)(ws+OFF_W2P) + (m-11)*65536;
        int i = blockIdx.x*64 + threadIdx.x;
        if (i < 65536){
            int k = i>>8, u = i&255;
            d[(k>>1)*512 + u*2 + (k&1)] = f2h(s[i]);
        }
        return;
    }
    const float* src; u16* dst; int K, N; int duo = 0;
    switch (m) {
      case 0: case 1: case 2:
        src = F + W_ENCU + m*196608; dst = (u16*)(ws+OFF_UP) + m*196608; K=256; N=768; break;
      case 3: case 4: case 5:
        src = F + W_ENCW + (m-3)*24576; dst = (u16*)(ws+OFF_WP) + (m-3)*24576; K=32; N=768; break;
      case 6:
        src = F + W_DECW; dst = (u16*)(ws+OFF_DWP); K=768; N=768; break;
      case 7:
        src = F + W_DECU; dst = (u16*)(ws+OFF_DUP); K=256; N=768; break;
      default:   // 8,9,10 -> att_W1[n], hi/lo f16
        src = F + W_AW1 + (m-8)*65536; dst = (u16*)(ws+OFF_W1P) + (m-8)*131072; K=256; N=256; duo=1; break;
    }
    int KT = K>>5, NT = N>>4;
    int tau = blockIdx.x;
    if (tau < KT*NT){
        int ct = tau / KT, kt = tau % KT;
        int l = threadIdx.x, q = l>>4, c = l&15;
        #pragma unroll
        for (int j = 0; j < 8; ++j){
            float v = src[(size_t)(kt*32 + q*8 + j)*N + ct*16 + c];
            u16 hi = f2h(v);
            size_t di = ((size_t)(ct*KT+kt)*64 + l)*8 + j;
            dst[di] = hi;
            if (duo) dst[65536 + di] = f2h(v - h2f(hi));
        }
    }
    if (blockIdx.x==0 && blockIdx.y==0 && threadIdx.x==0) put_sent(ws, 6);
}

// =========================================================================
// init: zero h0, C, pack0, counters
// =========================================================================
__global__ __launch_bounds__(256) void k_init(char* ws)
{
    long idx = (long)blockIdx.x*256 + threadIdx.x;
    if (idx < 65536) ((float*)(ws+OFF_H0))[idx] = 0.0f;
    else if (idx < 262144) ((float*)(ws+OFF_C))[idx-65536] = 0.0f;
    else if (idx < 393216) ((int*)(ws+OFF_PACK0))[idx-262144] = 0;
    if (idx < 32) ((unsigned*)(ws+OFF_CNT))[idx] = 0u;
}

// =========================================================================
// encoder GRU (MFMA, f16 recurrence): grid (16,3), 512 thr (8 waves).
// n-gate U in LDS; z/r-gate U pinned (128 regs -> lands in AGPRs of the
// unified file); only enc_W streams from L2. (round-4 proven BEST: the
// measured optimum of this family -- r13's 384-reg pin spilled at the
// 256 arch-VGPR cap, r2/r3's full streaming was L2-BW bound.)
// =========================================================================
__global__ __launch_bounds__(512, 2) void k_enc(const void* __restrict__ enc_in,
                                                char* __restrict__ ws,
                                                u16* __restrict__ enc_out)
{
    const float* __restrict__ F = (const float*)(ws+OFF_WF);
    int mode = *(const int*)(ws+OFF_FLAG);
    const int n  = blockIdx.y;
    const int b0 = blockIdx.x*16;
    const int tid = threadIdx.x;
    const int w = tid>>6, l = tid&63, quad = l>>4, c15 = l&15;

    __shared__ __align__(16) u16 hA[2][8][64][8];    // 16 KB
    __shared__ __align__(16) u16 sx[2][64][8];       //  2 KB
    __shared__ __align__(16) u16 nU[128][64][8];     // 128 KB: n-gate U frags

    const u16* __restrict__ upn = (const u16*)(ws+OFF_UP) + n*196608;   // KT=8
    const u16* __restrict__ wpn = (const u16*)(ws+OFF_WP) + n*24576;    // KT=1

    {
        const uint4* s4 = (const uint4*)(upn + 131072);
        uint4* d4 = (uint4*)&nU[0][0][0];
        for (int i = tid; i < 8192; i += 512) d4[i] = s4[i];
    }
    {
        int* z0 = (int*)&hA[0][0][0][0];
        for (int i = tid; i < 2048; i += 512) z0[i]=0;
    }
    float h[8];
    #pragma unroll
    for (int i=0;i<8;++i) h[i]=0.0f;

    float bzr[2], brr[2], bnr[2];
    #pragma unroll
    for (int si=0;si<2;++si){
        int u = (w*2+si)*16 + c15;
        bzr[si] = F[W_ENCB + n*768 + u];
        brr[si] = F[W_ENCB + n*768 + 256 + u];
        bnr[si] = F[W_ENCB + n*768 + 512 + u];
    }

    hfv8 Bz[2][8], Br[2][8];
    #pragma unroll
    for (int si=0;si<2;++si){
        int ct = w*2+si;
        #pragma unroll
        for (int kt=0;kt<8;++kt){
            Bz[si][kt] = *(const hfv8*)(upn + ((size_t)(ct*8+kt)*64 + l)*8);
            Br[si][kt] = *(const hfv8*)(upn + ((size_t)((16+ct)*8+kt)*64 + l)*8);
        }
    }
    #pragma unroll
    for (int si=0;si<2;++si)
        #pragma unroll
        for (int kt=0;kt<8;++kt)
            asm volatile("" : "+v"(Bz[si][kt]), "+v"(Br[si][kt]));

    const int mm = tid>>5, kk2 = tid&31;   // x staging map: 16 rows x 32 k
    sx[0][(kk2>>3)*16 + mm][kk2&7] =
        f2h(ldmix(enc_in, (((long)(n*BATCH + b0 + mm))*TLEN + 0)*32 + kk2, mode));
    __syncthreads();

    for (int t = 0; t < TLEN; ++t){
        int p = t & 1;
        int tt = (t+1 < TLEN) ? (t+1) : t;
        float xr = ldmix(enc_in, (((long)(n*BATCH + b0 + mm))*TLEN + tt)*32 + kk2, mode);

        hfv8 ah[8];
        #pragma unroll
        for (int kt=0; kt<8; ++kt)
            ah[kt] = *(const hfv8*)&hA[p][kt][l][0];
        hfv8 ax = *(const hfv8*)&sx[p][l][0];

        #pragma unroll
        for (int si=0; si<2; ++si){
            int ct = w*2 + si;
            f4v az  = {0.f,0.f,0.f,0.f};
            f4v ar  = {0.f,0.f,0.f,0.f};
            f4v anx = {0.f,0.f,0.f,0.f};
            f4v anh = {0.f,0.f,0.f,0.f};
            az  = MFMAH(ax, *(const hfv8*)(wpn + ((size_t)ct*64 + l)*8), az);
            ar  = MFMAH(ax, *(const hfv8*)(wpn + ((size_t)(16+ct)*64 + l)*8), ar);
            anx = MFMAH(ax, *(const hfv8*)(wpn + ((size_t)(32+ct)*64 + l)*8), anx);
            #pragma unroll
            for (int kt=0; kt<8; ++kt) az = MFMAH(ah[kt], Bz[si][kt], az);
            #pragma unroll
            for (int kt=0; kt<8; ++kt) ar = MFMAH(ah[kt], Br[si][kt], ar);
            #pragma unroll
            for (int kt=0; kt<8; ++kt)
                anh = MFMAH(ah[kt], *(const hfv8*)&nU[ct*8+kt][l][0], anh);
            int u = ct*16 + c15;
            #pragma unroll
            for (int j=0;j<4;++j){
                int m = quad*4 + j;
                float z = sigf(az[j] + bzr[si]);
                float r = sigf(ar[j] + brr[si]);
                float ng = tanh_fast(anx[j] + bnr[si] + r*anh[j]);
                float hn = (1.0f - z)*h[si*4+j] + z*ng;
                h[si*4+j] = hn;
                int kt = u>>5, q2 = (u>>3)&3, j2 = u&7;
                hA[1-p][kt][q2*16+m][j2] = f2h(hn);
            }
        }
        sx[1-p][(kk2>>3)*16 + mm][kk2&7] = f2h(xr);
        __syncthreads();
        {
            int c = tid & 31, m2 = tid >> 5;
            *reinterpret_cast<uint4*>(enc_out + (((long)(n*BATCH + b0 + m2))*TLEN + t)*256 + c*8) =
                *(const uint4*)&hA[1-p][c>>2][(c&3)*16 + m2][0];
        }
    }
    if (blockIdx.x==0 && blockIdx.y==0 && tid==0) put_sent(ws, 2);
}

// =========================================================================
// proj = enc_out @ att_W1[n] via f16 MFMA (W1 hi+lo -> ~f32 weight accuracy)
// grid (672 rowtiles64, 3), 256 thr (4 waves x 16 rows each)
// =========================================================================
__global__ __launch_bounds__(256) void k_projm(char* __restrict__ ws)
{
    const u16* __restrict__ enc16 = (const u16*)(ws+OFF_ENCOUT);
    const u16* __restrict__ w1p = (const u16*)(ws+OFF_W1P);
    u16* __restrict__ proj = (u16*)(ws+OFF_PROJ);
    const int n = blockIdx.y;
    const long r0 = (long)blockIdx.x*64;
    const int tid = threadIdx.x;
    const int w = tid>>6, l = tid&63, quad = l>>4, c15 = l&15;

    __shared__ __align__(16) u16 ob[64][264];

    const u16* erow = enc16 + ((long)n*43008 + r0 + w*16 + c15)*256;
    hfv8 a[8];
    #pragma unroll
    for (int kt=0; kt<8; ++kt)
        a[kt] = *(const hfv8*)(erow + kt*32 + quad*8);

    const u16* wb = w1p + (long)n*131072;
    #pragma unroll
    for (int ct=0; ct<16; ++ct){
        f4v acc = {0.f,0.f,0.f,0.f};
        #pragma unroll
        for (int kt=0; kt<8; ++kt)
            acc = MFMAH(a[kt], *(const hfv8*)(wb + ((size_t)(ct*8+kt)*64 + l)*8), acc);
        #pragma unroll
        for (int kt=0; kt<8; ++kt)
            acc = MFMAH(a[kt], *(const hfv8*)(wb + 65536 + ((size_t)(ct*8+kt)*64 + l)*8), acc);
        #pragma unroll
        for (int j=0;j<4;++j)
            ob[w*16 + quad*4 + j][ct*16 + c15] = f2h(acc[j]);
    }
    __syncthreads();
    for (int i = tid; i < 2048; i += 256){
        int r = i>>5, c = i&31;
        *reinterpret_cast<uint4*>(proj + ((long)n*43008 + r0 + r)*256 + c*8) =
            *(const uint4*)&ob[r][c*8];
    }
    if (blockIdx.x==0 && blockIdx.y==0 && tid==0) put_sent(ws, 3);
}

// =========================================================================
// decoder GRU step: grid (16 rowtiles16, 16 u-slices), 192 thr (wave=gate).
// A ([c,h] 16x1024) read PRE-PACKED f16 from ping-pong pack buffers.
// (round-4 proven version, unchanged)
// =========================================================================
__global__ __launch_bounds__(192) void k_dec_gru(
    char* __restrict__ ws, const float* __restrict__ h_in, float* __restrict__ h_out,
    const u16* __restrict__ packC, u16* __restrict__ packN,
    const void* __restrict__ dec_in, int step)
{
    const float* __restrict__ F = (const float*)(ws+OFF_WF);
    int mode = *(const int*)(ws+OFF_FLAG);
    const u16* __restrict__ dwp = (const u16*)(ws+OFF_DWP);   // KT=24
    const u16* __restrict__ dup = (const u16*)(ws+OFF_DUP);   // KT=8
    const int bx = blockIdx.x;
    const int b0 = bx*16;
    const int us = blockIdx.y;
    const int u0 = us*16;
    const int tid = threadIdx.x;
    const int gate = tid>>6, l = tid&63, quad = l>>4, c15 = l&15;
    const int ct = gate*16 + us;

    __shared__ float gz[16][16], gr[16][16], gx[16][16], gh[16][16];

    const u16* pA = packC + (size_t)bx*16384;   // [32][64][8] u16

    f4v accA  = {0.f,0.f,0.f,0.f};
    f4v accA2 = {0.f,0.f,0.f,0.f};
    f4v accB  = {0.f,0.f,0.f,0.f};
    f4v accB2 = {0.f,0.f,0.f,0.f};

    #pragma unroll
    for (int kg = 0; kg < 32; ++kg){
        hfv8 av = *(const hfv8*)(pA + ((size_t)kg*64 + l)*8);
        const u16* bp = (kg < 24) ? dwp + ((size_t)(ct*24 + kg)*64 + l)*8
                                  : dup + ((size_t)(ct*8  + (kg-24))*64 + l)*8;
        hfv8 bv = *(const hfv8*)bp;
        if (gate == 2 && kg >= 24){
            if (kg & 1) accB2 = MFMAH(av, bv, accB2);
            else        accB  = MFMAH(av, bv, accB);
        } else {
            if (kg & 1) accA2 = MFMAH(av, bv, accA2);
            else        accA  = MFMAH(av, bv, accA);
        }
    }
    accA = accA + accA2;
    accB = accB + accB2;

    #pragma unroll
    for (int j=0;j<4;++j){
        int m = quad*4 + j;
        if (gate == 0) gz[m][c15] = accA[j];
        else if (gate == 1) gr[m][c15] = accA[j];
        else { gx[m][c15] = accA[j]; gh[m][c15] = accB[j]; }
    }
    __syncthreads();
    for (int e = tid; e < 256; e += 192){
        int m = e>>4, j = e&15;
        int u = u0 + j;
        int b = b0 + m;
        float db = ldmix(dec_in, (long)b*HOR + step, mode);
        float sz = gz[m][j] + db*F[W_DECW + 768*768 + u]       + F[W_DECB + u];
        float sr = gr[m][j] + db*F[W_DECW + 768*768 + 256 + u] + F[W_DECB + 256 + u];
        float sn = gx[m][j] + db*F[W_DECW + 768*768 + 512 + u] + F[W_DECB + 512 + u];
        float z = sigf(sz);
        float r = sigf(sr);
        float ng = tanh_fast(sn + r*gh[m][j]);
        float hn = (1.0f - z)*h_in[(long)b*256 + u] + z*ng;
        h_out[(long)b*256 + u] = hn;
        // packed h (kg 24..31) for next step's A
        int kk = u & 31;
        int kg = 24 + (u >> 5);
        packN[(((size_t)bx*32 + kg)*64 + (kk>>3)*16 + m)*8 + (kk&7)] = f2h(hn);
    }
}

// =========================================================================
// attention v5 (round-10/12 proven BEST): grid (256 b, 3 n), 512 thr.
// - q-phase k-split across two half-blocks
// - phase 1: 8 waves x 21 t, 4 INDEPENDENT scalar loads per t
// - ctx: t-split across two half-blocks, 8 accumulator chains each
// =========================================================================
__global__ __launch_bounds__(512) void k_attn(char* __restrict__ ws,
                                              const float* __restrict__ hvec,
                                              u16* __restrict__ packN)
{
    const float* __restrict__ F = (const float*)(ws+OFF_WF);
    const u16* __restrict__ proj = (const u16*)(ws+OFF_PROJ);
    const u16* __restrict__ enc16 = (const u16*)(ws+OFF_ENCOUT);
    float* __restrict__ C = (float*)(ws+OFF_C);
    const int b = blockIdx.x, n = blockIdx.y;
    const int tid = threadIdx.x;
    const int w = tid>>6, l = tid&63;

    __shared__ float ps[TLEN][65];
    __shared__ float sc[TLEN];
    __shared__ float red[16];
    __shared__ float hrow[256];
    __shared__ float sq[256];
    __shared__ float sqp[2][256];
    __shared__ float ctxp[2][256];

    if (tid < 256) hrow[tid] = hvec[(long)b*256 + tid];
    __syncthreads();

    // q-phase: q[u] = sum_k h[b][k]*W2[n][k][u]; k-range split across halves
    {
        const u16* W2p = (const u16*)(ws+OFF_W2P) + n*65536;
        int uu = tid & 255, half = tid >> 8;
        float q0=0.f,q1=0.f,q2=0.f,q3=0.f;
        #pragma unroll 4
        for (int k2 = half*64; k2 < half*64+64; k2 += 2){
            unsigned va = *(const unsigned*)(W2p + (size_t)k2*512 + uu*2);
            unsigned vb = *(const unsigned*)(W2p + (size_t)(k2+1)*512 + uu*2);
            q0 += hrow[2*k2  ]*h2f((u16)(va & 0xffffu));
            q1 += hrow[2*k2+1]*h2f((u16)(va >> 16));
            q2 += hrow[2*k2+2]*h2f((u16)(vb & 0xffffu));
            q3 += hrow[2*k2+3]*h2f((u16)(vb >> 16));
        }
        sqp[half][uu] = (q0+q1)+(q2+q3);
    }
    __syncthreads();
    if (tid < 256) sq[tid] = sqp[0][tid] + sqp[1][tid];
    __syncthreads();

    float qv[4], vv[4];
    #pragma unroll
    for (int c4 = 0; c4 < 4; ++c4){
        qv[c4] = sq[c4*64 + l];
        vv[c4] = F[W_AV + n*256 + c4*64 + l];
    }
    long base = ((long)n*43008 + (long)b*TLEN)*256;
    const u16* pb = proj + base;

    // phase 1: per-(t,lane) partials, 8 waves x 21 t each
    for (int i = 0; i < 21; ++i){
        int t = w*21 + i;
        float s = 0.0f;
        #pragma unroll
        for (int c4 = 0; c4 < 4; ++c4){
            float pv = h2f(pb[(long)t*256 + c4*64 + l]);
            s += vv[c4]*tanh_fast(pv + qv[c4]);
        }
        ps[t][l] = s;
    }
    __syncthreads();

    // phase 2: lane-sum with 8 independent chains (t = tid < 168)
    float sval = 0.0f;
    if (tid < TLEN){
        float s0=0.f,s1=0.f,s2=0.f,s3=0.f,s4=0.f,s5=0.f,s6=0.f,s7=0.f;
        #pragma unroll
        for (int j = 0; j < 64; j += 8){
            s0 += ps[tid][j];   s1 += ps[tid][j+1];
            s2 += ps[tid][j+2]; s3 += ps[tid][j+3];
            s4 += ps[tid][j+4]; s5 += ps[tid][j+5];
            s6 += ps[tid][j+6]; s7 += ps[tid][j+7];
        }
        sval = ((s0+s1)+(s2+s3)) + ((s4+s5)+(s6+s7));
    }

    // parallel max (butterfly + 8-way LDS combine)
    float m = (tid < TLEN) ? sval : -1e30f;
    #pragma unroll
    for (int off = 32; off > 0; off >>= 1) m = fmaxf(m, __shfl_xor(m, off, 64));
    if (l == 0) red[w] = m;
    __syncthreads();
    float mx = fmaxf(fmaxf(fmaxf(red[0],red[1]), fmaxf(red[2],red[3])),
                     fmaxf(fmaxf(red[4],red[5]), fmaxf(red[6],red[7])));

    // exp + parallel sum
    float ex = 0.0f;
    if (tid < TLEN){ ex = __expf(sval - mx); sc[tid] = ex; }
    float su = ex;
    #pragma unroll
    for (int off = 32; off > 0; off >>= 1) su += __shfl_xor(su, off, 64);
    if (l == 0) red[8+w] = su;
    __syncthreads();
    float inv = frcp(((red[8]+red[9])+(red[10]+red[11])) +
                     ((red[12]+red[13])+(red[14]+red[15])));

    // ctx: t-range split across two half-blocks, 8 chains each (88=11*8, 80=10*8)
    {
        const u16* eb = enc16 + base;
        int uu = tid & 255, half = tid >> 8;
        int t0 = half ? 88 : 0;
        int t1 = half ? 168 : 88;
        float a0=0.f,a1=0.f,a2=0.f,a3=0.f,a4=0.f,a5=0.f,a6=0.f,a7=0.f;
        for (int t = t0; t < t1; t += 8){
            a0 += sc[t  ]*h2f(eb[(long)(t  )*256 + uu]);
            a1 += sc[t+1]*h2f(eb[(long)(t+1)*256 + uu]);
            a2 += sc[t+2]*h2f(eb[(long)(t+2)*256 + uu]);
            a3 += sc[t+3]*h2f(eb[(long)(t+3)*256 + uu]);
            a4 += sc[t+4]*h2f(eb[(long)(t+4)*256 + uu]);
            a5 += sc[t+5]*h2f(eb[(long)(t+5)*256 + uu]);
            a6 += sc[t+6]*h2f(eb[(long)(t+6)*256 + uu]);
            a7 += sc[t+7]*h2f(eb[(long)(t+7)*256 + uu]);
        }
        ctxp[half][uu] = (((a0+a1)+(a2+a3)) + ((a4+a5)+(a6+a7)));
    }
    __syncthreads();
    if (tid < 256){
        float cv = (ctxp[0][tid] + ctxp[1][tid])*inv;
        C[(long)b*768 + n*256 + tid] = cv;
        int kg = n*8 + (tid>>5), kk = tid&31;
        packN[(((size_t)(b>>4)*32 + kg)*64 + (kk>>3)*16 + (b&15))*8 + (kk&7)] = f2h(cv);
    }
    if (b==0 && n==0 && tid==0) put_sent(ws, 4);
}

// =========================================================================
// head1: sp = [h,c] @ out1_W[0:1024] : grid 32 rowtiles8, 256 thr
// =========================================================================
__global__ __launch_bounds__(256) void k_head1(char* ws, const float* h_last)
{
    const float* F = (const float*)(ws+OFF_WF);
    const float* C = (const float*)(ws+OFF_C);
    float* SP = (float*)(ws+OFF_SP);
    const int b0 = blockIdx.x*8;
    const int tid = threadIdx.x;

    __shared__ float A[8][1024];
    for (int i = tid; i < 8192; i += 256){
        int r = i >> 10, k = i & 1023;
        A[r][k] = (k < 256) ? h_last[(long)(b0+r)*256 + k]
                            : C[(long)(b0+r)*768 + (k-256)];
    }
    __syncthreads();

    const float* W = F + W_O1W;
    float acc[8];
    float bc = F[W_O1B + tid];
    #pragma unroll
    for (int r = 0; r < 8; ++r) acc[r] = bc;
    for (int k = 0; k < 1024; ++k){
        float w = W[k*256 + tid];
        #pragma unroll
        for (int r = 0; r < 8; ++r) acc[r] += A[r][k]*w;
    }
    for (int r = 0; r < 8; ++r)
        SP[(long)(b0+r)*256 + tid] = acc[r];
}

// =========================================================================
// ext: E = relu(ext_feat @ ext_W + ext_b) -> bf16 : grid 96, 256 thr
// =========================================================================
__global__ __launch_bounds__(256) void k_ext(const void* ext_feat, char* ws)
{
    const float* F = (const float*)(ws+OFF_WF);
    u16* E = (u16*)(ws+OFF_E);
    int mode = *(const int*)(ws+OFF_FLAG);
    const int r0 = blockIdx.x*64;
    const int tid = threadIdx.x;
    __shared__ float ef[64][16];
    for (int i = tid; i < 1024; i += 256)
        ef[i>>4][i&15] = ldmix(ext_feat, (long)(r0 + (i>>4))*16 + (i&15), mode);
    float wreg[16];
    #pragma unroll
    for (int k = 0; k < 16; ++k) wreg[k] = F[W_EXTW + k*256 + tid];
    float bb = F[W_EXTB + tid];
    __syncthreads();
    for (int r = 0; r < 64; ++r){
        float a = bb;
        #pragma unroll
        for (int k = 0; k < 16; ++k) a += ef[r][k]*wreg[k];
        E[(long)(r0+r)*256 + tid] = f2bf((a > 0.0f) ? a : 0.0f);
    }
}

// =========================================================================
// head2: x1 = relu(sp[b] + E@out1_W[1024:] + b1); out = x1@out2_W + b2
// =========================================================================
__global__ __launch_bounds__(256) void k_head2(char* ws, void* out)
{
    const float* F = (const float*)(ws+OFF_WF);
    const u16* E = (const u16*)(ws+OFF_E);
    const float* SP = (const float*)(ws+OFF_SP);
    int mode = *(const int*)(ws+OFF_FLAG);
    const int r0 = blockIdx.x*16;
    const int tid = threadIdx.x;
    const int w = tid>>6, l = tid&63;

    __shared__ float A[16][256];
    __shared__ float x1[16][257];
    for (int i = tid; i < 4096; i += 256)
        A[i>>8][i&255] = bf2f(E[(long)r0*256 + i]);
    __syncthreads();

    const float* W = F + W_O1W + 1024*256;
    float acc[16];
    float bc = F[W_O1B + tid];
    #pragma unroll
    for (int r = 0; r < 16; ++r) acc[r] = 0.0f;
    for (int k = 0; k < 256; ++k){
        float wv = W[k*256 + tid];
        #pragma unroll
        for (int r = 0; r < 16; ++r) acc[r] += A[r][k]*wv;
    }
    for (int r = 0; r < 16; ++r){
        int g = r0 + r;
        int b = g / HOR;
        float v = acc[r] + SP[(long)b*256 + tid] + bc;
        x1[r][tid] = (v > 0.0f) ? v : 0.0f;
    }
    __syncthreads();

    float w2v[4];
    #pragma unroll
    for (int c4 = 0; c4 < 4; ++c4) w2v[c4] = F[W_O2W + c4*64 + l];
    float b2 = F[W_O2B];
    #pragma unroll
    for (int rr = 0; rr < 4; ++rr){
        int m = w*4 + rr;
        float s = 0.0f;
        #pragma unroll
        for (int c4 = 0; c4 < 4; ++c4) s += x1[m][c4*64 + l]*w2v[c4];
        for (int off = 32; off > 0; off >>= 1) s += __shfl_xor(s, off, 64);
        if (l == 0){
            float val = s + b2;
            long g = r0 + m;
            if (mode == 0) ((u16*)out)[g] = f2bf(val);
            else           ((float*)out)[g] = val;
        }
    }
    if (blockIdx.x==0 && tid==0) put_sent(ws, 5);
}

// =========================================================================
// checker: writes 400+10*i to out[0] if sentinel i missing
// =========================================================================
__global__ __launch_bounds__(64) void MTANet_7593502179851_kernel(char* ws, void* out)
{
    if (threadIdx.x == 0){
        const unsigned int* sent = (const unsigned int*)(ws+OFF_SENT);
        int mode = *(const int*)(ws+OFF_FLAG);
        for (int i = 0; i < 7; ++i){
            if (sent[i] != (SENT_MAGIC | (unsigned int)i)){
                float code = 400.0f + 10.0f*(float)i;
                if (mode == 0) ((u16*)out)[0] = f2bf(code);
                else           ((float*)out)[0] = code;
                break;
            }
        }
    }
}

__global__ __launch_bounds__(64) void k_diag(void* out, float code)
{
    if (threadIdx.x == 0){
        ((u16*)out)[0] = f2bf(code);
        ((float*)out)[1] = code;
    }
}

// =========================================================================
extern "C" void kernel_launch(void* const* d_in, const int* in_sizes, int n_in,
                              void* d_out, int out_size, void* d_ws, size_t ws_size,
                              hipStream_t stream)
{
    char* ws = (char*)d_ws;

    static const int exp_sizes[18] = {
        4128768, 6144, 98304, 73728, 589824, 2304, 196608, 196608, 768,
        590592, 196608, 768, 4096, 256, 327680, 256, 256, 1 };
    int bad_i = -1;
    if (n_in != 18) bad_i = 99;
    else for (int i = 0; i < 18; ++i)
        if (in_sizes[i] != exp_sizes[i]){ bad_i = i; break; }
    if (bad_i >= 0){
        k_diag<<<dim3(1), dim3(64), 0, stream>>>(d_out, 900.0f + (float)bad_i);
        return;
    }
    if (ws_size < (size_t)NEED_BYTES){
        k_diag<<<dim3(1), dim3(64), 0, stream>>>(d_out, 600.0f);
        return;
    }

    P15 wp;
    for (int i = 0; i < 15; ++i) wp.p[i] = d_in[3+i];

    hipError_t le[12];
    for (int i = 0; i < 12; ++i) le[i] = hipSuccess;
    (void)hipGetLastError();
    #define CHK(slot) { hipError_t e_ = hipGetLastError(); if (e_ != hipSuccess && le[slot] == hipSuccess) le[slot] = e_; }

    k_probe<<<dim3(1), dim3(256), 0, stream>>>((const u16*)d_in[3], ws);       CHK(0)
    k_convert<<<dim3(256,15), dim3(256), 0, stream>>>(wp, ws);                 CHK(1)
    k_pack<<<dim3(1152,14), dim3(64), 0, stream>>>(ws);                        CHK(2)
    k_init<<<dim3(1536), dim3(256), 0, stream>>>(ws);                          CHK(3)
    k_enc<<<dim3(16,3), dim3(512), 0, stream>>>(d_in[0], ws, (u16*)(ws+OFF_ENCOUT)); CHK(4)
    k_projm<<<dim3(672,3), dim3(256), 0, stream>>>(ws);                        CHK(5)

    float* hbuf0 = (float*)(ws+OFF_H0);
    float* hbuf1 = (float*)(ws+OFF_H1);
    u16* pk0 = (u16*)(ws+OFF_PACK0);
    u16* pk1 = (u16*)(ws+OFF_PACK1);
    float* h_last = hbuf0;
    for (int s = 0; s < HOR; ++s){
        float* h_in  = (s & 1) ? hbuf1 : hbuf0;
        float* h_out = (s & 1) ? hbuf0 : hbuf1;
        u16* pc = (s & 1) ? pk1 : pk0;
        u16* pn = (s & 1) ? pk0 : pk1;
        k_dec_gru<<<dim3(16,16), dim3(192), 0, stream>>>(ws, h_in, h_out, pc, pn, d_in[1], s); CHK(6)
        k_attn<<<dim3(256,3), dim3(512), 0, stream>>>(ws, h_out, pn);           CHK(7)
        h_last = h_out;
    }
    k_head1<<<dim3(32), dim3(256), 0, stream>>>(ws, h_last);                   CHK(8)
    k_ext<<<dim3(96), dim3(256), 0, stream>>>(d_in[2], ws);                    CHK(9)
    k_head2<<<dim3(384), dim3(256), 0, stream>>>(ws, d_out);                   CHK(10)
    MTANet_7593502179851_kernel<<<dim3(1), dim3(64), 0, stream>>>(ws, d_out);
    #undef CHK

    for (int i = 0; i < 12; ++i){
        if (le[i] != hipSuccess){
            k_diag<<<dim3(1), dim3(64), 0, stream>>>(d_out, 800.0f + (float)i);
            break;
        }
    }
}